// Round 7
// baseline (57.071 us; speedup 1.0000x reference)
//
#include <hip/hip_runtime.h>

#define NG   4000
#define EPG  512
#define NROW (NG * 64)   // 256000 rows of x

// ---- prep: p = W1*(W2*(W3*1)); out[0..63]=p, out[64]=b1.q2, out[65]=b2.w3, out[66]=64*sum(b3)
__global__ __launch_bounds__(256) void prep_vec(
    const float* __restrict__ W1, const float* __restrict__ b1,
    const float* __restrict__ W2, const float* __restrict__ b2,
    const float* __restrict__ W3, const float* __restrict__ b3,
    float* __restrict__ out)
{
    __shared__ float M[4096];
    __shared__ float w3[64], q2[64];
    const int t = threadIdx.x;
    const int row = t >> 2, q = t & 3;

    for (int i = t; i < 1024; i += 256) ((float4*)M)[i] = ((const float4*)W3)[i];
    __syncthreads();
    {
        float acc = 0.f;
        #pragma unroll
        for (int i = 0; i < 16; ++i) acc += M[row * 64 + q * 16 + i];
        acc += __shfl_down(acc, 2, 4);
        acc += __shfl_down(acc, 1, 4);
        if (q == 0) w3[row] = acc;
    }
    __syncthreads();

    for (int i = t; i < 1024; i += 256) ((float4*)M)[i] = ((const float4*)W2)[i];
    __syncthreads();
    {
        float acc = 0.f;
        #pragma unroll
        for (int i = 0; i < 16; ++i) {
            const int c = q * 16 + i;
            acc += M[row * 64 + c] * w3[c];
        }
        acc += __shfl_down(acc, 2, 4);
        acc += __shfl_down(acc, 1, 4);
        if (q == 0) q2[row] = acc;
    }
    __syncthreads();

    for (int i = t; i < 1024; i += 256) ((float4*)M)[i] = ((const float4*)W1)[i];
    __syncthreads();
    {
        float acc = 0.f;
        #pragma unroll
        for (int i = 0; i < 16; ++i) {
            const int c = q * 16 + i;
            acc += M[row * 64 + c] * q2[c];
        }
        acc += __shfl_down(acc, 2, 4);
        acc += __shfl_down(acc, 1, 4);
        if (q == 0) out[row] = acc;
    }

    if (t < 64) {
        float t1 = b1[t] * q2[t];
        float t2 = b2[t] * w3[t];
        float t3 = b3[t];
        #pragma unroll
        for (int off = 32; off > 0; off >>= 1) {
            t1 += __shfl_down(t1, off, 64);
            t2 += __shfl_down(t2, off, 64);
            t3 += __shfl_down(t3, off, 64);
        }
        if (t == 0) { out[64] = t1; out[65] = t2; out[66] = 64.f * t3; }
    }
}

// ---- streaming GEMV: xp[r] = dot(x[r,:], p) — pure HBM-bound, no graph structure ----
__global__ __launch_bounds__(256) void gemv_xp(
    const float* __restrict__ x, const float* __restrict__ pv,
    float* __restrict__ xp)
{
    const int t = threadIdx.x;
    const float4 p4 = *(const float4*)(pv + (t & 15) * 4);   // L1-hot broadcast
    const int nchunk = NROW / 16;                            // 16 rows per block-iter
    for (int chunk = blockIdx.x; chunk < nchunk; chunk += gridDim.x) {
        const float4 v = ((const float4*)x)[(size_t)chunk * 256 + t];  // coalesced 4 KB
        float part = v.x * p4.x + v.y * p4.y + v.z * p4.z + v.w * p4.w;
        part += __shfl_down(part, 8, 16);
        part += __shfl_down(part, 4, 16);
        part += __shfl_down(part, 2, 16);
        part += __shfl_down(part, 1, 16);
        if ((t & 15) == 0) xp[chunk * 16 + (t >> 4)] = part;
    }
}

// ---- graph chain: one wave per graph, zero barriers, no x traffic ----
__global__ __launch_bounds__(256, 8) void graph_y(
    const int* __restrict__ ei, const float* __restrict__ pv,
    const float* __restrict__ xp, float* __restrict__ y, int etot)
{
    __shared__ float s_zd [4][64];
    __shared__ float s_acc[4][64];
    __shared__ int   s_deg[4][64];

    const int t = threadIdx.x, w = t >> 6, lane = t & 63;
    const int g = blockIdx.x * 4 + w;
    const int base = g * 64;

    float* zd  = s_zd [w];
    float* acc = s_acc[w];
    int*   deg = s_deg[w];

    // all global loads up front (small, coalesced)
    const float xpv = xp[base + lane];
    const int4* sp = (const int4*)(ei + (size_t)g * EPG);
    const int4* dp = (const int4*)(ei + (size_t)etot + (size_t)g * EPG);
    const int4 sA = sp[lane], sB = sp[lane + 64];
    const int4 dA = dp[lane], dB = dp[lane + 64];

    deg[lane] = 0;

    int se[8], de[8];
    se[0] = sA.x - base; se[1] = sA.y - base; se[2] = sA.z - base; se[3] = sA.w - base;
    se[4] = sB.x - base; se[5] = sB.y - base; se[6] = sB.z - base; se[7] = sB.w - base;
    de[0] = dA.x - base; de[1] = dA.y - base; de[2] = dA.z - base; de[3] = dA.w - base;
    de[4] = dB.x - base; de[5] = dB.y - base; de[6] = dB.z - base; de[7] = dB.w - base;

    // degree (wave-private int atomics, in-order LDS pipe)
    #pragma unroll
    for (int e = 0; e < 8; ++e) atomicAdd(&deg[de[e]], 1);
    const float dr = rsqrtf((float)(deg[lane] + 1));   // +1 self-loop

    // three passes: u[s] = dr[s]*sum_{e:(s,d)} dr[d]*z[d] + dr[s]^2*z[s]
    float zprev = 1.f;
    float u1, u2, u3;
    #pragma unroll
    for (int pass = 0; pass < 3; ++pass) {
        zd[lane]  = dr * zprev;
        acc[lane] = 0.f;
        #pragma unroll
        for (int e = 0; e < 8; ++e)
            atomicAdd(&acc[se[e]], zd[de[e]]);         // wave-private scatter
        const float u = dr * acc[lane] + dr * dr * zprev;
        if (pass == 0) u1 = u; else if (pass == 1) u2 = u; else u3 = u;
        zprev = u;
    }

    // per-lane contraction + wave reduce
    float r = u3 * xpv, a1 = u1, a2 = u2;
    #pragma unroll
    for (int off = 32; off > 0; off >>= 1) {
        r  += __shfl_down(r,  off, 64);
        a1 += __shfl_down(a1, off, 64);
        a2 += __shfl_down(a2, off, 64);
    }
    if (lane == 0) {
        const float beta1 = pv[64], beta2 = pv[65], beta3 = pv[66];
        y[g] = (r + a2 * beta1 + a1 * beta2 + beta3) * (1.0f / 4096.0f);
    }
}

extern "C" void kernel_launch(void* const* d_in, const int* in_sizes, int n_in,
                              void* d_out, int out_size, void* d_ws, size_t ws_size,
                              hipStream_t stream) {
    const float* x  = (const float*)d_in[0];
    const int*   ei = (const int*)  d_in[1];
    const float* W1 = (const float*)d_in[2];
    const float* b1 = (const float*)d_in[3];
    const float* W2 = (const float*)d_in[4];
    const float* b2 = (const float*)d_in[5];
    const float* W3 = (const float*)d_in[6];
    const float* b3 = (const float*)d_in[7];
    float* y = (float*)d_out;
    const int etot = in_sizes[1] / 2;     // 2,048,000

    float* pv = (float*)d_ws;                      // 67 floats
    float* xp = (float*)((char*)d_ws + 1024);      // 256000 floats

    hipLaunchKernelGGL(prep_vec, dim3(1), dim3(256), 0, stream,
                       W1, b1, W2, b2, W3, b3, pv);
    hipLaunchKernelGGL(gemv_xp, dim3(2048), dim3(256), 0, stream, x, pv, xp);
    hipLaunchKernelGGL(graph_y, dim3(NG / 4), dim3(256), 0, stream,
                       ei, pv, xp, y, etot);
}

// Round 8
// 51.840 us; speedup vs baseline: 1.1009x; 1.1009x over previous
//
#include <hip/hip_runtime.h>

#define NG   4000
#define EPG  512

// ---- prep: p = W1*(W2*(W3*1)); out[0..63]=p, out[64]=b1.q2, out[65]=b2.w3, out[66]=64*sum(b3)
__global__ __launch_bounds__(256) void prep_vec(
    const float* __restrict__ W1, const float* __restrict__ b1,
    const float* __restrict__ W2, const float* __restrict__ b2,
    const float* __restrict__ W3, const float* __restrict__ b3,
    float* __restrict__ out)
{
    __shared__ float M[4096];
    __shared__ float w3[64], q2[64];
    const int t = threadIdx.x;
    const int row = t >> 2, q = t & 3;

    for (int i = t; i < 1024; i += 256) ((float4*)M)[i] = ((const float4*)W3)[i];
    __syncthreads();
    {
        float acc = 0.f;
        #pragma unroll
        for (int i = 0; i < 16; ++i) acc += M[row * 64 + q * 16 + i];
        acc += __shfl_down(acc, 2, 4);
        acc += __shfl_down(acc, 1, 4);
        if (q == 0) w3[row] = acc;
    }
    __syncthreads();

    for (int i = t; i < 1024; i += 256) ((float4*)M)[i] = ((const float4*)W2)[i];
    __syncthreads();
    {
        float acc = 0.f;
        #pragma unroll
        for (int i = 0; i < 16; ++i) {
            const int c = q * 16 + i;
            acc += M[row * 64 + c] * w3[c];
        }
        acc += __shfl_down(acc, 2, 4);
        acc += __shfl_down(acc, 1, 4);
        if (q == 0) q2[row] = acc;
    }
    __syncthreads();

    for (int i = t; i < 1024; i += 256) ((float4*)M)[i] = ((const float4*)W1)[i];
    __syncthreads();
    {
        float acc = 0.f;
        #pragma unroll
        for (int i = 0; i < 16; ++i) {
            const int c = q * 16 + i;
            acc += M[row * 64 + c] * q2[c];
        }
        acc += __shfl_down(acc, 2, 4);
        acc += __shfl_down(acc, 1, 4);
        if (q == 0) out[row] = acc;
    }

    if (t < 64) {
        float t1 = b1[t] * q2[t];
        float t2 = b2[t] * w3[t];
        float t3 = b3[t];
        #pragma unroll
        for (int off = 32; off > 0; off >>= 1) {
            t1 += __shfl_down(t1, off, 64);
            t2 += __shfl_down(t2, off, 64);
            t3 += __shfl_down(t3, off, 64);
        }
        if (t == 0) { out[64] = t1; out[65] = t2; out[66] = 64.f * t3; }
    }
}

// ---- fused main: one wave per graph, zero barriers; x reduced to dot[k] at load time ----
__global__ __launch_bounds__(256, 4) void gcn3_fused(
    const float* __restrict__ x, const int* __restrict__ ei,
    const float* __restrict__ pv, float* __restrict__ y, int etot)
{
    __shared__ float s_zd [4][64];
    __shared__ float s_acc[4][64];
    __shared__ int   s_deg[4][64];

    const int t = threadIdx.x, w = t >> 6, lane = t & 63;
    const int g = blockIdx.x * 4 + w;
    const int base = g * 64;

    float* zd  = s_zd [w];
    float* acc = s_acc[w];
    int*   deg = s_deg[w];

    // p fragment for this lane's column slice (same 256 B for every block -> L1-hot)
    const float4 p4 = *(const float4*)(pv + (lane & 15) * 4);

    // ---- x streaming: coalesced float4 loads, consumed IMMEDIATELY into dot[k] ----
    // float4 (lane + 64k) covers row (lane>>4) + 4k, cols (lane&15)*4 .. +3
    const float4* xg = (const float4*)(x + (size_t)g * 4096);
    float dot[16];
    #pragma unroll
    for (int k = 0; k < 16; ++k) {
        const float4 v = xg[lane + 64 * k];
        dot[k] = v.x * p4.x + v.y * p4.y + v.z * p4.z + v.w * p4.w;
    }

    // ---- edges (4 coalesced int4 loads) ----
    const int4* sp = (const int4*)(ei + (size_t)g * EPG);
    const int4* dp = (const int4*)(ei + (size_t)etot + (size_t)g * EPG);
    const int4 sA = sp[lane], sB = sp[lane + 64];
    const int4 dA = dp[lane], dB = dp[lane + 64];

    deg[lane] = 0;

    int se[8], de[8];
    se[0] = sA.x - base; se[1] = sA.y - base; se[2] = sA.z - base; se[3] = sA.w - base;
    se[4] = sB.x - base; se[5] = sB.y - base; se[6] = sB.z - base; se[7] = sB.w - base;
    de[0] = dA.x - base; de[1] = dA.y - base; de[2] = dA.z - base; de[3] = dA.w - base;
    de[4] = dB.x - base; de[5] = dB.y - base; de[6] = dB.z - base; de[7] = dB.w - base;

    // degree (wave-private int atomics; in-order LDS pipe)
    #pragma unroll
    for (int e = 0; e < 8; ++e) atomicAdd(&deg[de[e]], 1);
    const float dr = rsqrtf((float)(deg[lane] + 1));   // +1 self-loop

    // three u-passes: u[s] = dr[s]*sum_{e:(s,d)} dr[d]*z[d] + dr[s]^2*z[s]
    float zprev = 1.f;
    float u1, u2, u3;
    #pragma unroll
    for (int pass = 0; pass < 3; ++pass) {
        zd[lane]  = dr * zprev;
        acc[lane] = 0.f;
        #pragma unroll
        for (int e = 0; e < 8; ++e)
            atomicAdd(&acc[se[e]], zd[de[e]]);         // wave-private scatter
        const float u = dr * acc[lane] + dr * dr * zprev;
        if (pass == 0) u1 = u; else if (pass == 1) u2 = u; else u3 = u;
        zprev = u;
    }

    // ---- contraction: r = sum_k u3[(lane>>4)+4k] * dot[k]  (broadcast LDS reads) ----
    zd[lane] = u3;
    float r = 0.f;
    #pragma unroll
    for (int k = 0; k < 16; ++k)
        r += zd[(lane >> 4) + 4 * k] * dot[k];

    // ---- wave reduce r, s1, s2 ----
    float a1 = u1, a2 = u2;
    #pragma unroll
    for (int off = 32; off > 0; off >>= 1) {
        r  += __shfl_down(r,  off, 64);
        a1 += __shfl_down(a1, off, 64);
        a2 += __shfl_down(a2, off, 64);
    }
    if (lane == 0) {
        const float beta1 = pv[64], beta2 = pv[65], beta3 = pv[66];
        y[g] = (r + a2 * beta1 + a1 * beta2 + beta3) * (1.0f / 4096.0f);
    }
}

extern "C" void kernel_launch(void* const* d_in, const int* in_sizes, int n_in,
                              void* d_out, int out_size, void* d_ws, size_t ws_size,
                              hipStream_t stream) {
    const float* x  = (const float*)d_in[0];
    const int*   ei = (const int*)  d_in[1];
    const float* W1 = (const float*)d_in[2];
    const float* b1 = (const float*)d_in[3];
    const float* W2 = (const float*)d_in[4];
    const float* b2 = (const float*)d_in[5];
    const float* W3 = (const float*)d_in[6];
    const float* b3 = (const float*)d_in[7];
    float* y = (float*)d_out;
    const int etot = in_sizes[1] / 2;     // 2,048,000

    float* pv = (float*)d_ws;             // 67 floats
    hipLaunchKernelGGL(prep_vec, dim3(1), dim3(256), 0, stream,
                       W1, b1, W2, b2, W3, b3, pv);
    hipLaunchKernelGGL(gcn3_fused, dim3(NG / 4), dim3(256), 0, stream,
                       x, ei, pv, y, etot);
}

// Round 9
// 49.578 us; speedup vs baseline: 1.1511x; 1.0456x over previous
//
#include <hip/hip_runtime.h>

#define NG   4000
#define EPG  512

__device__ inline float dot4(const float4 a, const float4 b) {
    return a.x * b.x + a.y * b.y + a.z * b.z + a.w * b.w;
}

// ---- prep: p = W1*(W2*(W3*1)); out[0..63]=p, out[64]=b1.q2, out[65]=b2.w3, out[66]=64*sum(b3)
// All W loads prefetched up front (one latency), then 3 shfl-reduced stages.
__global__ __launch_bounds__(256) void prep_vec(
    const float* __restrict__ W1, const float* __restrict__ b1,
    const float* __restrict__ W2, const float* __restrict__ b2,
    const float* __restrict__ W3, const float* __restrict__ b3,
    float* __restrict__ out)
{
    __shared__ float w3[64], q2[64];
    const int t  = threadIdx.x;
    const int rg = t >> 4;           // row-group: row = 16*j + rg for float4 #j
    const int l16 = t & 15;

    // prefetch everything (12 float4 per thread + bias scalars)
    const float4* W1_4 = (const float4*)W1;
    const float4* W2_4 = (const float4*)W2;
    const float4* W3_4 = (const float4*)W3;
    float4 a3[4], a2[4], a1[4];
    #pragma unroll
    for (int j = 0; j < 4; ++j) a3[j] = W3_4[t + 256 * j];
    #pragma unroll
    for (int j = 0; j < 4; ++j) a2[j] = W2_4[t + 256 * j];
    #pragma unroll
    for (int j = 0; j < 4; ++j) a1[j] = W1_4[t + 256 * j];
    float bb1 = 0.f, bb2 = 0.f, bb3 = 0.f;
    if (t < 64) { bb1 = b1[t]; bb2 = b2[t]; bb3 = b3[t]; }

    // stage 1: w3[r] = row-sum of W3
    #pragma unroll
    for (int j = 0; j < 4; ++j) {
        float s = a3[j].x + a3[j].y + a3[j].z + a3[j].w;
        s += __shfl_down(s, 8, 16);
        s += __shfl_down(s, 4, 16);
        s += __shfl_down(s, 2, 16);
        s += __shfl_down(s, 1, 16);
        if (l16 == 0) w3[16 * j + rg] = s;
    }
    __syncthreads();

    // stage 2: q2 = W2 * w3
    {
        const float4 wc = ((const float4*)w3)[l16];
        #pragma unroll
        for (int j = 0; j < 4; ++j) {
            float s = dot4(a2[j], wc);
            s += __shfl_down(s, 8, 16);
            s += __shfl_down(s, 4, 16);
            s += __shfl_down(s, 2, 16);
            s += __shfl_down(s, 1, 16);
            if (l16 == 0) q2[16 * j + rg] = s;
        }
    }
    __syncthreads();

    // stage 3: p = W1 * q2  (straight to out)
    {
        const float4 qc = ((const float4*)q2)[l16];
        #pragma unroll
        for (int j = 0; j < 4; ++j) {
            float s = dot4(a1[j], qc);
            s += __shfl_down(s, 8, 16);
            s += __shfl_down(s, 4, 16);
            s += __shfl_down(s, 2, 16);
            s += __shfl_down(s, 1, 16);
            if (l16 == 0) out[16 * j + rg] = s;
        }
    }

    // betas (one wave; q2/w3 valid after the stage-2 barrier)
    if (t < 64) {
        float t1 = bb1 * q2[t];
        float t2 = bb2 * w3[t];
        float t3 = bb3;
        #pragma unroll
        for (int off = 32; off > 0; off >>= 1) {
            t1 += __shfl_down(t1, off, 64);
            t2 += __shfl_down(t2, off, 64);
            t3 += __shfl_down(t3, off, 64);
        }
        if (t == 0) { out[64] = t1; out[65] = t2; out[66] = 64.f * t3; }
    }
}

// ---- main: one block per graph. Phase 1: 4 waves stream x -> xp. Phase 2: wave 0 runs chain.
__global__ __launch_bounds__(256, 8) void gcn3_main(
    const float* __restrict__ x, const int* __restrict__ ei,
    const float* __restrict__ pv, float* __restrict__ y, int etot)
{
    __shared__ float xp[64], zd[64], acc[64];
    __shared__ int   deg[64];

    const int t = threadIdx.x, w = t >> 6, lane = t & 63;
    const int g = blockIdx.x;
    const int base = g * 64;

    // p fragment for this thread's column slice (L1-hot broadcast)
    const float4 p4 = *(const float4*)(pv + (t & 15) * 4);

    // ---- x loads: 4 float4 per thread, coalesced (float4 idx t + 256j) ----
    const float4* xg = (const float4*)(x + (size_t)g * 4096);
    const float4 xa = xg[t], xb = xg[t + 256], xc = xg[t + 512], xd = xg[t + 768];

    // ---- edge loads on wave 0, issued early so latency hides under phase 1 ----
    int4 sA, sB, dA, dB;
    if (w == 0) {
        const int4* sp = (const int4*)(ei + (size_t)g * EPG);
        const int4* dp = (const int4*)(ei + (size_t)etot + (size_t)g * EPG);
        sA = sp[lane]; sB = sp[lane + 64];
        dA = dp[lane]; dB = dp[lane + 64];
        deg[lane] = 0;
    }

    // ---- dots + 16-lane shfl reduce -> xp[row], row = 16j + (t>>4) ----
    {
        float d0 = dot4(xa, p4), d1 = dot4(xb, p4), d2 = dot4(xc, p4), d3 = dot4(xd, p4);
        #pragma unroll
        for (int off = 8; off > 0; off >>= 1) {
            d0 += __shfl_down(d0, off, 16);
            d1 += __shfl_down(d1, off, 16);
            d2 += __shfl_down(d2, off, 16);
            d3 += __shfl_down(d3, off, 16);
        }
        if ((t & 15) == 0) {
            const int rg = t >> 4;
            xp[rg]      = d0;
            xp[16 + rg] = d1;
            xp[32 + rg] = d2;
            xp[48 + rg] = d3;
        }
    }
    __syncthreads();
    if (w != 0) return;          // waves 1-3 done; wave 0 owns the graph chain

    // ---- graph chain (wave-private LDS, in-order pipe, no barriers) ----
    int se[8], de[8];
    se[0] = sA.x - base; se[1] = sA.y - base; se[2] = sA.z - base; se[3] = sA.w - base;
    se[4] = sB.x - base; se[5] = sB.y - base; se[6] = sB.z - base; se[7] = sB.w - base;
    de[0] = dA.x - base; de[1] = dA.y - base; de[2] = dA.z - base; de[3] = dA.w - base;
    de[4] = dB.x - base; de[5] = dB.y - base; de[6] = dB.z - base; de[7] = dB.w - base;

    #pragma unroll
    for (int e = 0; e < 8; ++e) atomicAdd(&deg[de[e]], 1);
    const float dr = rsqrtf((float)(deg[lane] + 1));   // +1 self-loop

    float zprev = 1.f;
    float u1, u2, u3;
    #pragma unroll
    for (int pass = 0; pass < 3; ++pass) {
        zd[lane]  = dr * zprev;
        acc[lane] = 0.f;
        #pragma unroll
        for (int e = 0; e < 8; ++e)
            atomicAdd(&acc[se[e]], zd[de[e]]);         // wave-private scatter
        const float u = dr * acc[lane] + dr * dr * zprev;
        if (pass == 0) u1 = u; else if (pass == 1) u2 = u; else u3 = u;
        zprev = u;
    }

    // ---- contraction + wave reduce ----
    float r = u3 * xp[lane], a1 = u1, a2 = u2;
    #pragma unroll
    for (int off = 32; off > 0; off >>= 1) {
        r  += __shfl_down(r,  off, 64);
        a1 += __shfl_down(a1, off, 64);
        a2 += __shfl_down(a2, off, 64);
    }
    if (lane == 0) {
        const float beta1 = pv[64], beta2 = pv[65], beta3 = pv[66];
        y[g] = (r + a2 * beta1 + a1 * beta2 + beta3) * (1.0f / 4096.0f);
    }
}

extern "C" void kernel_launch(void* const* d_in, const int* in_sizes, int n_in,
                              void* d_out, int out_size, void* d_ws, size_t ws_size,
                              hipStream_t stream) {
    const float* x  = (const float*)d_in[0];
    const int*   ei = (const int*)  d_in[1];
    const float* W1 = (const float*)d_in[2];
    const float* b1 = (const float*)d_in[3];
    const float* W2 = (const float*)d_in[4];
    const float* b2 = (const float*)d_in[5];
    const float* W3 = (const float*)d_in[6];
    const float* b3 = (const float*)d_in[7];
    float* y = (float*)d_out;
    const int etot = in_sizes[1] / 2;     // 2,048,000

    float* pv = (float*)d_ws;             // 67 floats
    hipLaunchKernelGGL(prep_vec, dim3(1), dim3(256), 0, stream,
                       W1, b1, W2, b2, W3, b3, pv);
    hipLaunchKernelGGL(gcn3_main, dim3(NG), dim3(256), 0, stream,
                       x, ei, pv, y, etot);
}

// Round 10
// 23.450 us; speedup vs baseline: 2.4338x; 2.1142x over previous
//
#include <hip/hip_runtime.h>

#define NG      4000
#define EPG     512
#define CSTRIDE 35   // ints per Cnt row: 35 % 32 == 3 (odd) -> <=2-way LDS bank conflicts

__device__ inline float dot4(const float4 a, const float4 b) {
    return a.x * b.x + a.y * b.y + a.z * b.z + a.w * b.w;
}

// ---- prep: p = W1*(W2*(W3*1)); out[0..63]=p, out[64]=b1.q2, out[65]=b2.w3, out[66]=64*sum(b3)
__global__ __launch_bounds__(256) void prep_vec(
    const float* __restrict__ W1, const float* __restrict__ b1,
    const float* __restrict__ W2, const float* __restrict__ b2,
    const float* __restrict__ W3, const float* __restrict__ b3,
    float* __restrict__ out)
{
    __shared__ float w3[64], q2[64];
    const int t  = threadIdx.x;
    const int rg = t >> 4;           // row = 16*j + rg for float4 #j
    const int l16 = t & 15;

    const float4* W1_4 = (const float4*)W1;
    const float4* W2_4 = (const float4*)W2;
    const float4* W3_4 = (const float4*)W3;
    float4 a3[4], a2[4], a1[4];
    #pragma unroll
    for (int j = 0; j < 4; ++j) a3[j] = W3_4[t + 256 * j];
    #pragma unroll
    for (int j = 0; j < 4; ++j) a2[j] = W2_4[t + 256 * j];
    #pragma unroll
    for (int j = 0; j < 4; ++j) a1[j] = W1_4[t + 256 * j];
    float bb1 = 0.f, bb2 = 0.f, bb3 = 0.f;
    if (t < 64) { bb1 = b1[t]; bb2 = b2[t]; bb3 = b3[t]; }

    #pragma unroll
    for (int j = 0; j < 4; ++j) {
        float s = a3[j].x + a3[j].y + a3[j].z + a3[j].w;
        s += __shfl_down(s, 8, 16);
        s += __shfl_down(s, 4, 16);
        s += __shfl_down(s, 2, 16);
        s += __shfl_down(s, 1, 16);
        if (l16 == 0) w3[16 * j + rg] = s;
    }
    __syncthreads();

    {
        const float4 wc = ((const float4*)w3)[l16];
        #pragma unroll
        for (int j = 0; j < 4; ++j) {
            float s = dot4(a2[j], wc);
            s += __shfl_down(s, 8, 16);
            s += __shfl_down(s, 4, 16);
            s += __shfl_down(s, 2, 16);
            s += __shfl_down(s, 1, 16);
            if (l16 == 0) q2[16 * j + rg] = s;
        }
    }
    __syncthreads();

    {
        const float4 qc = ((const float4*)q2)[l16];
        #pragma unroll
        for (int j = 0; j < 4; ++j) {
            float s = dot4(a1[j], qc);
            s += __shfl_down(s, 8, 16);
            s += __shfl_down(s, 4, 16);
            s += __shfl_down(s, 2, 16);
            s += __shfl_down(s, 1, 16);
            if (l16 == 0) out[16 * j + rg] = s;
        }
    }

    if (t < 64) {
        float t1 = bb1 * q2[t];
        float t2 = bb2 * w3[t];
        float t3 = bb3;
        #pragma unroll
        for (int off = 32; off > 0; off >>= 1) {
            t1 += __shfl_down(t1, off, 64);
            t2 += __shfl_down(t2, off, 64);
            t3 += __shfl_down(t3, off, 64);
        }
        if (t == 0) { out[64] = t1; out[65] = t2; out[66] = 64.f * t3; }
    }
}

// ---- main: R5 structure (wide gather matvec), 8 blocks/CU, 6 barriers ----
__global__ __launch_bounds__(256, 8) void gcn3_collapse2(
    const float* __restrict__ x, const int* __restrict__ ei,
    const float* __restrict__ pv, float* __restrict__ y, int etot)
{
    __shared__ int   Cnt[64 * CSTRIDE];   // packed u16x2 counts, Cnt[s][d]  (8960 B)
    __shared__ int   deg4[4][64];         // per-wave degree copies         (1024 B)
    __shared__ float dinv[64], zdA[64], zdB[64], u1[64], u2[64], u3[64], xp[64];

    const int g = blockIdx.x, t = threadIdx.x;
    const int w = t >> 6;
    const int base = g * 64;
    const int row = t >> 2, q4 = t & 3;

    // x loads first: thread t covers 64 consecutive bytes -> wave reads 4 KB coalesced
    const float4* xg = (const float4*)(x + (size_t)g * 4096 + row * 64 + q4 * 16);
    const float4 xr0 = xg[0], xr1 = xg[1], xr2 = xg[2], xr3 = xg[3];

    // edges (2 per thread, coalesced)
    const int2 sv = *(const int2*)(ei + (size_t)g * EPG + 2 * t);
    const int2 dv = *(const int2*)(ei + (size_t)etot + (size_t)g * EPG + 2 * t);

    // p slice (same 256 B for all blocks -> L1-hot)
    const float4* pp = (const float4*)(pv + q4 * 16);
    const float4 p0 = pp[0], p1 = pp[1], p2 = pp[2], p3 = pp[3];

    // zero Cnt + deg4
    {
        const int4 z = {0, 0, 0, 0};
        int4* c4 = (int4*)Cnt;
        #pragma unroll 1
        for (int i = t; i < (64 * CSTRIDE) / 4; i += 256) c4[i] = z;
        ((int*)deg4)[t] = 0;
    }
    __syncthreads();                                   // B1

    // deterministic integer scatter (per-wave deg copies cut contention 4x)
    {
        const int sa = sv.x - base, da = dv.x - base;
        const int sb = sv.y - base, db = dv.y - base;
        atomicAdd(&deg4[w][da], 1);
        atomicAdd(&deg4[w][db], 1);
        atomicAdd(&Cnt[sa * CSTRIDE + (da >> 1)], 1 << ((da & 1) * 16));
        atomicAdd(&Cnt[sb * CSTRIDE + (db >> 1)], 1 << ((db & 1) * 16));
    }

    // xp[r] = dot(x[r,:], p) — register math + 4-lane shfl reduce
    {
        float part = dot4(xr0, p0) + dot4(xr1, p1) + dot4(xr2, p2) + dot4(xr3, p3);
        part += __shfl_down(part, 2, 4);
        part += __shfl_down(part, 1, 4);
        if (q4 == 0) xp[row] = part;
    }
    __syncthreads();                                   // B2 (covers atomics + xp)

    if (t < 64) {
        const int ds = deg4[0][t] + deg4[1][t] + deg4[2][t] + deg4[3][t];
        const float di = rsqrtf((float)(ds + 1));      // +1 = self-loop
        dinv[t] = di;
        zdA[t] = di;                                   // zd for pass 1 (z = 1)
    }
    __syncthreads();                                   // B3

    // u-pass: wide gather matvec, one barrier per pass (zd double-buffered)
    auto upass = [&](const float* zin, float* zout, const float* uprev, float* u) {
        const int* rp = Cnt + row * CSTRIDE + q4 * 8;
        float acc = 0.f;
        #pragma unroll
        for (int i = 0; i < 8; ++i) {
            const unsigned v = (unsigned)rp[i];
            const int d0 = q4 * 16 + 2 * i;
            acc += (float)(v & 0xffffu) * zin[d0];
            acc += (float)(v >> 16)     * zin[d0 + 1];
        }
        acc += __shfl_down(acc, 2, 4);
        acc += __shfl_down(acc, 1, 4);
        if (q4 == 0) {
            const float di = dinv[row];
            const float zp = uprev ? uprev[row] : 1.0f;
            const float uv = di * acc + di * di * zp;
            u[row] = uv;
            if (zout) zout[row] = di * uv;             // fused zd update (other buffer)
        }
        __syncthreads();
    };

    upass(zdA, zdB, nullptr, u1);                      // B4
    upass(zdB, zdA, u1,      u2);                      // B5
    upass(zdA, nullptr, u2,  u3);                      // B6

    // final: r = u3 . xp, s1 = sum(u1), s2 = sum(u2)
    if (t < 64) {
        float r  = u3[t] * xp[t];
        float a1 = u1[t];
        float a2 = u2[t];
        #pragma unroll
        for (int off = 32; off > 0; off >>= 1) {
            r  += __shfl_down(r,  off, 64);
            a1 += __shfl_down(a1, off, 64);
            a2 += __shfl_down(a2, off, 64);
        }
        if (t == 0) {
            const float beta1 = pv[64], beta2 = pv[65], beta3 = pv[66];
            y[g] = (r + a2 * beta1 + a1 * beta2 + beta3) * (1.0f / 4096.0f);
        }
    }
}

extern "C" void kernel_launch(void* const* d_in, const int* in_sizes, int n_in,
                              void* d_out, int out_size, void* d_ws, size_t ws_size,
                              hipStream_t stream) {
    const float* x  = (const float*)d_in[0];
    const int*   ei = (const int*)  d_in[1];
    const float* W1 = (const float*)d_in[2];
    const float* b1 = (const float*)d_in[3];
    const float* W2 = (const float*)d_in[4];
    const float* b2 = (const float*)d_in[5];
    const float* W3 = (const float*)d_in[6];
    const float* b3 = (const float*)d_in[7];
    float* y = (float*)d_out;
    const int etot = in_sizes[1] / 2;     // 2,048,000

    float* pv = (float*)d_ws;             // 67 floats
    hipLaunchKernelGGL(prep_vec, dim3(1), dim3(256), 0, stream,
                       W1, b1, W2, b2, W3, b3, pv);
    hipLaunchKernelGGL(gcn3_collapse2, dim3(NG), dim3(256), 0, stream,
                       x, ei, pv, y, etot);
}